// Round 8
// baseline (386.083 us; speedup 1.0000x reference)
//
#include <hip/hip_runtime.h>

#define NPTS   16384
#define KCODES 8192
#define DDIM   256
#define HWSZ   1024
#define CHW    (DDIM * HWSZ)          // 262144
#define OUT_ELEMS 4194304
#define LOSS_OFF  OUT_ELEMS
#define IDX_OFF   (OUT_ELEMS + 1)

#define PTB   64                 // points per block
#define CTILE 128                // codes per tile
#define KC    64                 // k per staged chunk
#define NIT   256                // 64 tiles x 4 chunks; image index == it
#define XPITCH 264               // x f16 pitch (528 B = 4 mod 32 banks -> 2-way, free)

typedef _Float16 half_t;
typedef __attribute__((ext_vector_type(8))) _Float16 half8;
typedef __attribute__((ext_vector_type(4))) float     v4f;

union HU { _Float16 h; unsigned short u; };

#define EHI_WORDS  (256 * 8192)                 // ushorts (4 MB)
#define SE_OFF_B   (2 * EHI_WORDS * 2)          // byte offset of se[] in ws

#define GLD16(gp, lp) __builtin_amdgcn_global_load_lds( \
    (const __attribute__((address_space(1))) unsigned int*)(gp), \
    (__attribute__((address_space(3))) unsigned int*)(lp), 16, 0, 0)

// ---- prep: split emb to f16 hi/lo (bit-identical formula to R7 staging),
// ---- pre-swizzled image layout, plus se[k] = ||e_k||^2 (fp32) ----
// (Identical to the proven R9 prep.)
__global__ void prep_kernel(const float* __restrict__ emb,
                            unsigned short* __restrict__ ehi,
                            unsigned short* __restrict__ elo,
                            float* __restrict__ se)
{
    const int gw   = (blockIdx.x * 256 + threadIdx.x) >> 6;   // 0..1023
    const int lane = threadIdx.x & 63;
    for (int i = 0; i < 8; ++i) {
        const int c = gw * 8 + i;                             // code 0..8191
        const float4 v = *(const float4*)(emb + (size_t)c * DDIM + lane * 4);
        float ps = v.x * v.x;
        ps = fmaf(v.y, v.y, ps); ps = fmaf(v.z, v.z, ps); ps = fmaf(v.w, v.w, ps);
        float tot = ps;
        #pragma unroll
        for (int off = 1; off < 64; off <<= 1) tot += __shfl_xor(tot, off);
        if (lane == 0) se[c] = tot;
        const float E0 = v.x * 64.f, E1 = v.y * 64.f, E2 = v.z * 64.f, E3 = v.w * 64.f;
        const half_t h0 = (half_t)E0, h1 = (half_t)E1, h2 = (half_t)E2, h3 = (half_t)E3;
        const half_t l0 = (half_t)((E0 - (float)h0) * 2048.f);
        const half_t l1 = (half_t)((E1 - (float)h1) * 2048.f);
        const half_t l2 = (half_t)((E2 - (float)h2) * 2048.f);
        const half_t l3 = (half_t)((E3 - (float)h3) * 2048.f);
        HU a0, a1, a2, a3, b0, b1, b2, b3;
        a0.h = h0; a1.h = h1; a2.h = h2; a3.h = h3;
        b0.h = l0; b1.h = l1; b2.h = l2; b3.h = l3;
        const unsigned int uh0 = (unsigned)a0.u | ((unsigned)a1.u << 16);
        const unsigned int uh1 = (unsigned)a2.u | ((unsigned)a3.u << 16);
        const unsigned int ul0 = (unsigned)b0.u | ((unsigned)b1.u << 16);
        const unsigned int ul1 = (unsigned)b2.u | ((unsigned)b3.u << 16);
        const int ck = lane >> 4;                 // chunk 0..3 (k block of 64)
        const int kb = (lane & 15) >> 1;          // 16B block within row, 0..7
        const int hf = lane & 1;                  // half-block
        const int T = c >> 7, r = c & 127;
        const size_t base = (((size_t)(T * 4 + ck) * 128 + r) * 64)
                          + (size_t)((kb ^ (r & 7)) * 8) + hf * 4;
        *(unsigned int*)&ehi[base]     = uh0;
        *(unsigned int*)&ehi[base + 2] = uh1;
        *(unsigned int*)&elo[base]     = ul0;
        *(unsigned int*)&elo[base + 2] = ul1;
    }
}

// m = x.e via 3 f16 MFMAs (exact pow2 scalings, R7-identical):
//   m = (hh + (xh.el + xl.eh)*2^-11) / 64
// dist = fl(fl(s+se) - 2m) fp32, lowest-index tie-break (proven R1-R7).
// R9:  A-fragments hoisted to regs (225 us). R10-R15 all regressed.
// R16: cross-chunk REGISTER double-buffer of B-fragments. R9's 2110 cy/chunk
//   = MFMA 931 + LDS 1024 SUMMED: chunk ck's ds_reads must follow ck's
//   barrier and immediately feed ck's MFMAs -> LDS and matrix pipes
//   serialize by dependency. Fix: during ck's MFMAs (pure-register; A
//   hoisted, B in regs), prefetch ck+1's 8 b128 fragments into the other
//   register set. Barriers unchanged (syncthreads' lgkmcnt(0) kills WAR on
//   re-DMA'd buffers; vmcnt(0) publishes the one-phase-old STAGE, exactly
//   R9's proven gap). MFMA order/operands bit-identical to R9. ck is a
//   compile-time literal (4 unrolled phases); frag sets are two named
//   arrays, constant-indexed only (rule #20). sched_barrier(0) per phase
//   pins {reads, STAGE} before the MFMA cluster.
// NOTE: never pass a second __launch_bounds__ arg on this toolchain (R4).
__launch_bounds__(512)
__global__ void vq_kernel(const float* __restrict__ x,
                          const unsigned short* __restrict__ ehi,
                          const unsigned short* __restrict__ elo,
                          const float* __restrict__ wse,
                          const float* __restrict__ emb,
                          float* __restrict__ out)
{
    __shared__ __align__(16) unsigned short ldsXH[PTB][XPITCH];   // 33792 B
    __shared__ __align__(16) unsigned short ldsXL[PTB][XPITCH];   // 33792 B
    __shared__ __align__(16) unsigned short ldsEH[2][8192];       // 32768 B
    __shared__ __align__(16) unsigned short ldsEL[2][8192];       // 32768 B
    __shared__ float  ldsRS[8][65];
    __shared__ float  ldsS[PTB];
    __shared__ float  ldsFD[8][32];
    __shared__ int    ldsFI[8][32];
    __shared__ int    ldsI[PTB];
    __shared__ double ldsL[8];

    const int t    = threadIdx.x;
    const int lane = t & 63;
    const int w    = t >> 6;          // 0..7
    const int n0   = blockIdx.x * PTB;
    const int b    = n0 / HWSZ;
    const int hw0  = n0 % HWSZ;
    const float* xs = x + (size_t)b * CHW + hw0;   // xs[c*HWSZ + p]

    // ---- e-chunk DMA staging: 32 KB/iter; waves 0-3 hi, 4-7 lo; 4x1KB calls ----
    const int part = (w & 3) * 4096;               // byte sub-range
    #define STAGE(img, buf) do { \
        const char* _g = (const char*)((w < 4) ? ehi : elo) \
                       + (size_t)(img) * 16384 + part + lane * 16; \
        char* _l = (char*)((w < 4) ? ldsEH[buf] : ldsEL[buf]) + part; \
        GLD16(_g,          _l); \
        GLD16(_g + 1024,   _l + 1024); \
        GLD16(_g + 2048,   _l + 2048); \
        GLD16(_g + 3072,   _l + 3072); \
    } while (0)

    STAGE(0, 0);   // bootstrap chunk 0 (drained by prologue barrier)

    // ---- prologue: stage x split hi/lo (f16), accumulate s[p]=||x_p||^2 ----
    {
        const int p   = t & 63;
        const int seg = t >> 6;
        float a = 0.f;
        for (int i = 0; i < 32; ++i) {
            const int c = seg * 32 + i;
            const float v = xs[(size_t)c * HWSZ + p];
            const half_t hh = (half_t)v;
            const half_t hl = (half_t)((v - (float)hh) * 2048.0f);
            HU u0; u0.h = hh; ldsXH[p][c] = u0.u;
            HU u1; u1.h = hl; ldsXL[p][c] = u1.u;
            a = fmaf(v, v, a);
        }
        ldsRS[seg][p] = a;
    }
    __syncthreads();
    if (t < PTB) {
        float s = 0.f;
        for (int g = 0; g < 8; ++g) s += ldsRS[g][t];
        ldsS[t] = s;
    }
    __syncthreads();

    const int h32 = (w & 1) * 32;     // pt-half base row
    const int q32 = (w >> 1) * 32;    // code-quarter base within tile
    const int ln  = lane & 15;
    const int qd  = lane >> 4;        // 0..3

    float s_frag[8];
    #pragma unroll
    for (int pbi = 0; pbi < 2; ++pbi)
        #pragma unroll
        for (int r = 0; r < 4; ++r)
            s_frag[pbi * 4 + r] = ldsS[h32 + pbi * 16 + qd * 4 + r];

    // ---- A-fragment hoist: this wave's 32 x-rows, full K=256, hi+lo ----
    half8 aH[2][4][2], aL[2][4][2];   // [pt-block][ck][kk], 128 VGPR
    #pragma unroll
    for (int pb = 0; pb < 2; ++pb)
        #pragma unroll
        for (int ck = 0; ck < 4; ++ck)
            #pragma unroll
            for (int kk = 0; kk < 2; ++kk) {
                const int ka = ck * KC + kk * 32 + qd * 8;
                aH[pb][ck][kk] = *(const half8*)&ldsXH[h32 + pb * 16 + ln][ka];
                aL[pb][ck][kk] = *(const half8*)&ldsXL[h32 + pb * 16 + ln][ka];
            }

    float best_d[8]; int best_i[8];
    #pragma unroll
    for (int i = 0; i < 8; ++i) { best_d[i] = 3.4e38f; best_i[i] = 0; }

    v4f acc_hh[2][2], acc_hl[2][2];
    float se0 = 0.f, se1 = 0.f;

    const int rL = (q32 + ln) * 64;
    const int rH = (q32 + 16 + ln) * 64;

    // B-fragment register double buffer: 8 half8 per set (kk0: 0..3, kk1: 4..7)
    half8 bA[8], bB[8];

    #define READF(SET, BUF) do { \
        _Pragma("unroll") \
        for (int kk = 0; kk < 2; ++kk) { \
            const int swz = ((kk * 4 + qd) ^ (ln & 7)) * 8; \
            SET[kk * 4 + 0] = *(const half8*)&ldsEH[BUF][rL + swz]; \
            SET[kk * 4 + 1] = *(const half8*)&ldsEH[BUF][rH + swz]; \
            SET[kk * 4 + 2] = *(const half8*)&ldsEL[BUF][rL + swz]; \
            SET[kk * 4 + 3] = *(const half8*)&ldsEL[BUF][rH + swz]; \
        } \
    } while (0)

    // 24 MFMAs on a fragment set; order identical to R9 (per kk: hh x4,
    // aH.bl x4, aL.bh x4)
    #define MFMAC(SET, CK) do { \
        _Pragma("unroll") \
        for (int kk = 0; kk < 2; ++kk) { \
            const half8 bh0 = SET[kk * 4 + 0], bh1 = SET[kk * 4 + 1]; \
            const half8 bl0 = SET[kk * 4 + 2], bl1 = SET[kk * 4 + 3]; \
            acc_hh[0][0] = __builtin_amdgcn_mfma_f32_16x16x32_f16(aH[0][CK][kk], bh0, acc_hh[0][0], 0, 0, 0); \
            acc_hh[0][1] = __builtin_amdgcn_mfma_f32_16x16x32_f16(aH[0][CK][kk], bh1, acc_hh[0][1], 0, 0, 0); \
            acc_hh[1][0] = __builtin_amdgcn_mfma_f32_16x16x32_f16(aH[1][CK][kk], bh0, acc_hh[1][0], 0, 0, 0); \
            acc_hh[1][1] = __builtin_amdgcn_mfma_f32_16x16x32_f16(aH[1][CK][kk], bh1, acc_hh[1][1], 0, 0, 0); \
            acc_hl[0][0] = __builtin_amdgcn_mfma_f32_16x16x32_f16(aH[0][CK][kk], bl0, acc_hl[0][0], 0, 0, 0); \
            acc_hl[0][1] = __builtin_amdgcn_mfma_f32_16x16x32_f16(aH[0][CK][kk], bl1, acc_hl[0][1], 0, 0, 0); \
            acc_hl[1][0] = __builtin_amdgcn_mfma_f32_16x16x32_f16(aH[1][CK][kk], bl0, acc_hl[1][0], 0, 0, 0); \
            acc_hl[1][1] = __builtin_amdgcn_mfma_f32_16x16x32_f16(aH[1][CK][kk], bl1, acc_hl[1][1], 0, 0, 0); \
            acc_hl[0][0] = __builtin_amdgcn_mfma_f32_16x16x32_f16(aL[0][CK][kk], bh0, acc_hl[0][0], 0, 0, 0); \
            acc_hl[0][1] = __builtin_amdgcn_mfma_f32_16x16x32_f16(aL[0][CK][kk], bh1, acc_hl[0][1], 0, 0, 0); \
            acc_hl[1][0] = __builtin_amdgcn_mfma_f32_16x16x32_f16(aL[1][CK][kk], bh0, acc_hl[1][0], 0, 0, 0); \
            acc_hl[1][1] = __builtin_amdgcn_mfma_f32_16x16x32_f16(aL[1][CK][kk], bh1, acc_hl[1][1], 0, 0, 0); \
        } \
    } while (0)

    // prime the pipeline: chunk 0 frags -> bA (buf0 published by prologue
    // barriers); then issue chunk 1's DMA.
    READF(bA, 0);
    STAGE(1, 1);

    for (int tile = 0; tile < 64; ++tile) {
        const int it0 = tile * 4;
        // ---- phase 0: MFMA chunk it0 (bA); prefetch it0+1 -> bB; DMA it0+2 ----
        __syncthreads();                  // publishes buf1 (it0+1); drains bA-src reads
        READF(bB, 1);
        STAGE(it0 + 2, 0);
        __builtin_amdgcn_sched_barrier(0);
        #pragma unroll
        for (int i = 0; i < 2; ++i)
            #pragma unroll
            for (int j = 0; j < 2; ++j)
                #pragma unroll
                for (int r = 0; r < 4; ++r) { acc_hh[i][j][r] = 0.f; acc_hl[i][j][r] = 0.f; }
        MFMAC(bA, 0);
        // ---- phase 1: MFMA it0+1 (bB); prefetch it0+2 -> bA; DMA it0+3 ----
        __syncthreads();
        READF(bA, 0);
        STAGE(it0 + 3, 1);
        __builtin_amdgcn_sched_barrier(0);
        MFMAC(bB, 1);
        // ---- phase 2: MFMA it0+2 (bA); prefetch it0+3 -> bB; DMA it0+4; se ----
        __syncthreads();
        READF(bB, 1);
        if (tile < 63) STAGE(it0 + 4, 0);
        se0 = wse[tile * CTILE + q32 + ln];
        se1 = wse[tile * CTILE + q32 + 16 + ln];
        __builtin_amdgcn_sched_barrier(0);
        MFMAC(bA, 2);
        // ---- phase 3: MFMA it0+3 (bB); prefetch next tile ck0 -> bA; DMA ----
        __syncthreads();
        if (tile < 63) {
            READF(bA, 0);
            STAGE(it0 + 5, 1);
        }
        __builtin_amdgcn_sched_barrier(0);
        MFMAC(bB, 3);
        // ---- tile finalize: dist = fl(fl(s+se) - 2m), ascending code order ----
        {
            const int tb = tile * CTILE;
            #pragma unroll
            for (int csi = 0; csi < 2; ++csi) {
                const float se   = csi ? se1 : se0;
                const int   code = tb + q32 + csi * 16 + ln;
                #pragma unroll
                for (int pbi = 0; pbi < 2; ++pbi)
                    #pragma unroll
                    for (int r = 0; r < 4; ++r) {
                        const float m  = fmaf(acc_hl[pbi][csi][r], 4.8828125e-4f,
                                              acc_hh[pbi][csi][r]) * 0.015625f;
                        const float T  = s_frag[pbi * 4 + r] + se;
                        const float dd = fmaf(-2.0f, m, T);
                        const int   s  = pbi * 4 + r;
                        if (dd < best_d[s]) { best_d[s] = dd; best_i[s] = code; }
                    }
            }
        }
    }

    // ---- argmin reduce: butterfly over the 16-lane col group (lexicographic) ----
    #pragma unroll
    for (int off = 1; off < 16; off <<= 1) {
        #pragma unroll
        for (int s = 0; s < 8; ++s) {
            const float d2 = __shfl_xor(best_d[s], off);
            const int   i2 = __shfl_xor(best_i[s], off);
            if (d2 < best_d[s] || (d2 == best_d[s] && i2 < best_i[s])) {
                best_d[s] = d2; best_i[s] = i2;
            }
        }
    }
    if (ln == 0) {
        #pragma unroll
        for (int pbi = 0; pbi < 2; ++pbi)
            #pragma unroll
            for (int r = 0; r < 4; ++r) {
                ldsFD[w][pbi * 16 + qd * 4 + r] = best_d[pbi * 4 + r];
                ldsFI[w][pbi * 16 + qd * 4 + r] = best_i[pbi * 4 + r];
            }
    }
    __syncthreads();
    if (t < PTB) {
        const int hh  = t >> 5;
        const int r32 = t & 31;
        float bd = 3.4e38f; int bi = 0;
        #pragma unroll
        for (int qq = 0; qq < 4; ++qq) {
            const int wv = hh + qq * 2;
            const float d2 = ldsFD[wv][r32];
            const int   i2 = ldsFI[wv][r32];
            if (d2 < bd || (d2 == bd && i2 < bi)) { bd = d2; bi = i2; }
        }
        ldsI[t] = bi;
        out[(size_t)IDX_OFF + n0 + t] = (float)bi;
    }
    __syncthreads();

    // ---- epilogue: gather e row, straight-through out, loss partial ----
    double lsum = 0.0;
    {
        const int p  = t & 63;
        const int cg = t >> 6;
        const int row = ldsI[p];
        const float* erow = emb + (size_t)row * DDIM;
        float* ob = out + (size_t)b * CHW + hw0 + p;
        for (int q = 0; q < 32; ++q) {
            const int c = cg * 32 + q;
            const float e  = erow[c];
            const float xx = xs[(size_t)c * HWSZ + p];
            const float diff = e - xx;             // fl(x_q - xt)
            ob[(size_t)c * HWSZ] = xx + diff;      // straight-through rounding
            lsum += (double)diff * (double)diff;
        }
    }
    #pragma unroll
    for (int off = 32; off > 0; off >>= 1)
        lsum += __shfl_xor(lsum, off);
    if ((t & 63) == 0) ldsL[t >> 6] = lsum;
    __syncthreads();
    if (t == 0) {
        double tot = 0.0;
        #pragma unroll
        for (int wv = 0; wv < 8; ++wv) tot += ldsL[wv];
        atomicAdd(&out[LOSS_OFF], (float)(tot * (1.25 / 4194304.0)));
    }
}

extern "C" void kernel_launch(void* const* d_in, const int* in_sizes, int n_in,
                              void* d_out, int out_size, void* d_ws, size_t ws_size,
                              hipStream_t stream) {
    (void)in_sizes; (void)n_in; (void)out_size; (void)ws_size;
    const float* x   = (const float*)d_in[0];
    const float* emb = (const float*)d_in[1];
    float* out = (float*)d_out;
    unsigned short* ehi = (unsigned short*)d_ws;
    unsigned short* elo = ehi + EHI_WORDS;
    float*          wse = (float*)((char*)d_ws + SE_OFF_B);
    hipMemsetAsync((char*)d_out + (size_t)LOSS_OFF * sizeof(float), 0, sizeof(float), stream);
    prep_kernel<<<256, 256, 0, stream>>>(emb, ehi, elo, wse);
    vq_kernel<<<NPTS / PTB, 512, 0, stream>>>(x, ehi, elo, wse, emb, out);
}

// Round 9
// 278.593 us; speedup vs baseline: 1.3858x; 1.3858x over previous
//
#include <hip/hip_runtime.h>

#define NPTS   16384
#define KCODES 8192
#define DDIM   256
#define HWSZ   1024
#define CHW    (DDIM * HWSZ)          // 262144
#define OUT_ELEMS 4194304
#define LOSS_OFF  OUT_ELEMS
#define IDX_OFF   (OUT_ELEMS + 1)

#define PTB   64                 // points per block
#define CTILE 128                // codes per tile
#define KC    64                 // k per staged chunk
#define NIT   256                // 64 tiles x 4 chunks; image index == it
#define XPITCH 264               // x f16 pitch (528 B = 4 mod 32 banks -> 2-way, free)

// LDS arena: FOUR e-buffers, buf q in {0..3}: EH at q*32768, EL at q*32768+16384
// (128 KB). X (prologue-only, DEAD after A-hoist) aliases the front: XH at 0
// (33792 B), XL at 33792 (33792 B). ALL e-staging is issued after the
// post-hoist full-drain __syncthreads (R12/R13-proven aliasing discipline).
#define ARENA_B 131072
#define XH_OFF  0
#define XL_OFF  33792

typedef _Float16 half_t;
typedef __attribute__((ext_vector_type(8))) _Float16 half8;
typedef __attribute__((ext_vector_type(4))) float     v4f;

union HU { _Float16 h; unsigned short u; };

#define EHI_WORDS  (256 * 8192)                 // ushorts (4 MB)
#define SE_OFF_B   (2 * EHI_WORDS * 2)          // byte offset of se[] in ws

#define GLD16(gp, lp) __builtin_amdgcn_global_load_lds( \
    (const __attribute__((address_space(1))) unsigned int*)(gp), \
    (__attribute__((address_space(3))) unsigned int*)(lp), 16, 0, 0)

// ---- prep: split emb to f16 hi/lo (bit-identical formula to R7 staging),
// ---- pre-swizzled image layout, plus se[k] = ||e_k||^2 (fp32) ----
// (Identical to the proven R9 prep.)
__global__ void prep_kernel(const float* __restrict__ emb,
                            unsigned short* __restrict__ ehi,
                            unsigned short* __restrict__ elo,
                            float* __restrict__ se)
{
    const int gw   = (blockIdx.x * 256 + threadIdx.x) >> 6;   // 0..1023
    const int lane = threadIdx.x & 63;
    for (int i = 0; i < 8; ++i) {
        const int c = gw * 8 + i;                             // code 0..8191
        const float4 v = *(const float4*)(emb + (size_t)c * DDIM + lane * 4);
        float ps = v.x * v.x;
        ps = fmaf(v.y, v.y, ps); ps = fmaf(v.z, v.z, ps); ps = fmaf(v.w, v.w, ps);
        float tot = ps;
        #pragma unroll
        for (int off = 1; off < 64; off <<= 1) tot += __shfl_xor(tot, off);
        if (lane == 0) se[c] = tot;
        const float E0 = v.x * 64.f, E1 = v.y * 64.f, E2 = v.z * 64.f, E3 = v.w * 64.f;
        const half_t h0 = (half_t)E0, h1 = (half_t)E1, h2 = (half_t)E2, h3 = (half_t)E3;
        const half_t l0 = (half_t)((E0 - (float)h0) * 2048.f);
        const half_t l1 = (half_t)((E1 - (float)h1) * 2048.f);
        const half_t l2 = (half_t)((E2 - (float)h2) * 2048.f);
        const half_t l3 = (half_t)((E3 - (float)h3) * 2048.f);
        HU a0, a1, a2, a3, b0, b1, b2, b3;
        a0.h = h0; a1.h = h1; a2.h = h2; a3.h = h3;
        b0.h = l0; b1.h = l1; b2.h = l2; b3.h = l3;
        const unsigned int uh0 = (unsigned)a0.u | ((unsigned)a1.u << 16);
        const unsigned int uh1 = (unsigned)a2.u | ((unsigned)a3.u << 16);
        const unsigned int ul0 = (unsigned)b0.u | ((unsigned)b1.u << 16);
        const unsigned int ul1 = (unsigned)b2.u | ((unsigned)b3.u << 16);
        const int ck = lane >> 4;                 // chunk 0..3 (k block of 64)
        const int kb = (lane & 15) >> 1;          // 16B block within row, 0..7
        const int hf = lane & 1;                  // half-block
        const int T = c >> 7, r = c & 127;
        const size_t base = (((size_t)(T * 4 + ck) * 128 + r) * 64)
                          + (size_t)((kb ^ (r & 7)) * 8) + hf * 4;
        *(unsigned int*)&ehi[base]     = uh0;
        *(unsigned int*)&ehi[base + 2] = uh1;
        *(unsigned int*)&elo[base]     = ul0;
        *(unsigned int*)&elo[base + 2] = ul1;
    }
}

// m = x.e via 3 f16 MFMAs (exact pow2 scalings, R7-identical):
//   m = (hh + (xh.el + xl.eh)*2^-11) / 64
// dist = fl(fl(s+se) - 2m) fp32, lowest-index tie-break (proven R1-R7).
// R9:  A-frag hoist, 225 us. Structure = the guide's measured "2-phase stall"
//   (syncthreads full-drain per chunk -> LDS phase + MFMA phase SUM).
// R17: faithful T3/T4/T5 template port (the proven +28-73% GEMM schedule):
//   4 LDS buffers (buf = ck&3, X aliased under them), 8 fine phases per tile
//   {4 ds_reads | 2 global_load_lds for chunk it+2 | counted vmcnt(4) once
//   per chunk | s_barrier | setprio(1) 12 MFMA setprio(0) | s_barrier}.
//   NO __syncthreads / vmcnt(0) in-loop (tail: one vmcnt(0) at chunk 254);
//   NO sched_barrier (R16/m141 lesson). Compiler manages lgkmcnt (plain C++
//   LDS reads, register-dep tracked). vmcnt(4) math: the 4 newest vmem ops
//   at each wait are this chunk's own stages (for it+2); all older publishes
//   (it+1's buffer) are forced complete; se loads issue AFTER the wait so
//   they never pollute the count. WAR margin 2 chunks on every buffer.
//   MFMA sequence byte-identical to R9 -> bit-identical results.
// NOTE: never pass a second __launch_bounds__ arg on this toolchain (R4).
__launch_bounds__(512)
__global__ void vq_kernel(const float* __restrict__ x,
                          const unsigned short* __restrict__ ehi,
                          const unsigned short* __restrict__ elo,
                          const float* __restrict__ wse,
                          const float* __restrict__ emb,
                          float* __restrict__ out)
{
    __shared__ __align__(16) char ldsA[ARENA_B];
    __shared__ float  ldsRS[8][65];
    __shared__ float  ldsS[PTB];
    __shared__ float  ldsFD[8][32];
    __shared__ int    ldsFI[8][32];
    __shared__ int    ldsI[PTB];
    __shared__ double ldsL[8];

    const int t    = threadIdx.x;
    const int lane = t & 63;
    const int w    = t >> 6;          // 0..7
    const int n0   = blockIdx.x * PTB;
    const int b    = n0 / HWSZ;
    const int hw0  = n0 % HWSZ;
    const float* xs = x + (size_t)b * CHW + hw0;   // xs[c*HWSZ + p]

    unsigned short* XHp = (unsigned short*)(ldsA + XH_OFF);
    unsigned short* XLp = (unsigned short*)(ldsA + XL_OFF);

    // ---- e-chunk DMA staging: 32 KB/chunk; waves 0-3 hi, 4-7 lo;
    //      2x1KB calls per half (half = kk phase) ----
    const int part = (w & 3) * 4096;               // byte sub-range
    #define STAGE_HALF(img, q, hf) do { \
        const char* _g = (const char*)((w < 4) ? ehi : elo) \
                       + (size_t)(img) * 16384 + part + (hf) * 2048 + lane * 16; \
        char* _l = ldsA + (size_t)(q) * 32768 + ((w < 4) ? 0 : 16384) + part + (hf) * 2048; \
        GLD16(_g,          _l); \
        GLD16(_g + 1024,   _l + 1024); \
    } while (0)

    // ---- prologue: stage x split hi/lo (f16), accumulate s[p]=||x_p||^2 ----
    // (X lives in the arena; NO e-staging before the post-hoist drain.)
    {
        const int p   = t & 63;
        const int seg = t >> 6;
        float a = 0.f;
        for (int i = 0; i < 32; ++i) {
            const int c = seg * 32 + i;
            const float v = xs[(size_t)c * HWSZ + p];
            const half_t hh = (half_t)v;
            const half_t hl = (half_t)((v - (float)hh) * 2048.0f);
            HU u0; u0.h = hh; XHp[p * XPITCH + c] = u0.u;
            HU u1; u1.h = hl; XLp[p * XPITCH + c] = u1.u;
            a = fmaf(v, v, a);
        }
        ldsRS[seg][p] = a;
    }
    __syncthreads();
    if (t < PTB) {
        float s = 0.f;
        for (int g = 0; g < 8; ++g) s += ldsRS[g][t];
        ldsS[t] = s;
    }
    __syncthreads();

    const int h32 = (w & 1) * 32;     // pt-half base row
    const int q32 = (w >> 1) * 32;    // code-quarter base within tile
    const int ln  = lane & 15;
    const int qd  = lane >> 4;        // 0..3

    float s_frag[8];
    #pragma unroll
    for (int pbi = 0; pbi < 2; ++pbi)
        #pragma unroll
        for (int r = 0; r < 4; ++r)
            s_frag[pbi * 4 + r] = ldsS[h32 + pbi * 16 + qd * 4 + r];

    // ---- A-fragment hoist: this wave's 32 x-rows, full K=256, hi+lo ----
    half8 aH[2][4][2], aL[2][4][2];   // [pt-block][ck][kk], 128 VGPR
    #pragma unroll
    for (int pb = 0; pb < 2; ++pb)
        #pragma unroll
        for (int ck = 0; ck < 4; ++ck)
            #pragma unroll
            for (int kk = 0; kk < 2; ++kk) {
                const int ka = ck * KC + kk * 32 + qd * 8;
                aH[pb][ck][kk] = *(const half8*)&XHp[(h32 + pb * 16 + ln) * XPITCH + ka];
                aL[pb][ck][kk] = *(const half8*)&XLp[(h32 + pb * 16 + ln) * XPITCH + ka];
            }
    // X region DEAD; e-bufs alias it. __syncthreads (full lgkm/vm drain in
    // every wave) orders all X reads before the first DMA below.
    __syncthreads();

    // bootstrap: chunks 0,1 -> bufs 0,1; publish buf0 (allow buf1's 4 in flight)
    STAGE_HALF(0, 0, 0); STAGE_HALF(0, 0, 1);
    STAGE_HALF(1, 1, 0); STAGE_HALF(1, 1, 1);
    asm volatile("s_waitcnt vmcnt(4)" ::: "memory");
    __builtin_amdgcn_s_barrier();

    float best_d[8]; int best_i[8];
    #pragma unroll
    for (int i = 0; i < 8; ++i) { best_d[i] = 3.4e38f; best_i[i] = 0; }

    v4f acc_hh[2][2], acc_hl[2][2];
    float se0 = 0.f, se1 = 0.f;

    const int rL = (q32 + ln) * 64;
    const int rH = (q32 + 16 + ln) * 64;

    // 12 MFMAs, order identical to R9 (hh x4, aH.bl x4, aL.bh x4)
    #define MFMA12(CK, KK, BH0, BH1, BL0, BL1) do { \
        acc_hh[0][0] = __builtin_amdgcn_mfma_f32_16x16x32_f16(aH[0][CK][KK], BH0, acc_hh[0][0], 0, 0, 0); \
        acc_hh[0][1] = __builtin_amdgcn_mfma_f32_16x16x32_f16(aH[0][CK][KK], BH1, acc_hh[0][1], 0, 0, 0); \
        acc_hh[1][0] = __builtin_amdgcn_mfma_f32_16x16x32_f16(aH[1][CK][KK], BH0, acc_hh[1][0], 0, 0, 0); \
        acc_hh[1][1] = __builtin_amdgcn_mfma_f32_16x16x32_f16(aH[1][CK][KK], BH1, acc_hh[1][1], 0, 0, 0); \
        acc_hl[0][0] = __builtin_amdgcn_mfma_f32_16x16x32_f16(aH[0][CK][KK], BL0, acc_hl[0][0], 0, 0, 0); \
        acc_hl[0][1] = __builtin_amdgcn_mfma_f32_16x16x32_f16(aH[0][CK][KK], BL1, acc_hl[0][1], 0, 0, 0); \
        acc_hl[1][0] = __builtin_amdgcn_mfma_f32_16x16x32_f16(aH[1][CK][KK], BL0, acc_hl[1][0], 0, 0, 0); \
        acc_hl[1][1] = __builtin_amdgcn_mfma_f32_16x16x32_f16(aH[1][CK][KK], BL1, acc_hl[1][1], 0, 0, 0); \
        acc_hl[0][0] = __builtin_amdgcn_mfma_f32_16x16x32_f16(aL[0][CK][KK], BH0, acc_hl[0][0], 0, 0, 0); \
        acc_hl[0][1] = __builtin_amdgcn_mfma_f32_16x16x32_f16(aL[0][CK][KK], BH1, acc_hl[0][1], 0, 0, 0); \
        acc_hl[1][0] = __builtin_amdgcn_mfma_f32_16x16x32_f16(aL[1][CK][KK], BH0, acc_hl[1][0], 0, 0, 0); \
        acc_hl[1][1] = __builtin_amdgcn_mfma_f32_16x16x32_f16(aL[1][CK][KK], BH1, acc_hl[1][1], 0, 0, 0); \
    } while (0)

    // one fine phase: 4 ds_reads | stage half of chunk it+2 | (phase B only:
    // counted vmcnt publishing buf ck+1, then se on ck==2) | barrier |
    // prio(1) 12 MFMA prio(0) | barrier.
    #define PHASE(CK, KK) do { \
        const unsigned short* EHp_ = (const unsigned short*)(ldsA + (CK) * 32768); \
        const unsigned short* ELp_ = EHp_ + 8192; \
        const int swz_ = (((KK) * 4 + qd) ^ (ln & 7)) * 8; \
        const half8 bh0_ = *(const half8*)&EHp_[rL + swz_]; \
        const half8 bh1_ = *(const half8*)&EHp_[rH + swz_]; \
        const half8 bl0_ = *(const half8*)&ELp_[rL + swz_]; \
        const half8 bl1_ = *(const half8*)&ELp_[rH + swz_]; \
        const int it_ = it0 + (CK); \
        if (it_ + 2 < NIT) STAGE_HALF(it_ + 2, ((CK) + 2) & 3, KK); \
        if ((KK) == 1) { \
            if (it_ + 2 < NIT)      { asm volatile("s_waitcnt vmcnt(4)" ::: "memory"); } \
            else if (it_ + 1 < NIT) { asm volatile("s_waitcnt vmcnt(0)" ::: "memory"); } \
            if ((CK) == 2) { \
                se0 = wse[tile * CTILE + q32 + ln]; \
                se1 = wse[tile * CTILE + q32 + 16 + ln]; \
            } \
        } \
        __builtin_amdgcn_s_barrier(); \
        __builtin_amdgcn_s_setprio(1); \
        MFMA12(CK, KK, bh0_, bh1_, bl0_, bl1_); \
        __builtin_amdgcn_s_setprio(0); \
        __builtin_amdgcn_s_barrier(); \
    } while (0)

    for (int tile = 0; tile < 64; ++tile) {
        const int it0 = tile * 4;
        #pragma unroll
        for (int i = 0; i < 2; ++i)
            #pragma unroll
            for (int j = 0; j < 2; ++j)
                #pragma unroll
                for (int r = 0; r < 4; ++r) { acc_hh[i][j][r] = 0.f; acc_hl[i][j][r] = 0.f; }

        PHASE(0, 0); PHASE(0, 1);
        PHASE(1, 0); PHASE(1, 1);
        PHASE(2, 0); PHASE(2, 1);
        PHASE(3, 0); PHASE(3, 1);

        // ---- tile finalize: dist = fl(fl(s+se) - 2m), ascending code order ----
        {
            const int tb = tile * CTILE;
            #pragma unroll
            for (int csi = 0; csi < 2; ++csi) {
                const float se   = csi ? se1 : se0;
                const int   code = tb + q32 + csi * 16 + ln;
                #pragma unroll
                for (int pbi = 0; pbi < 2; ++pbi)
                    #pragma unroll
                    for (int r = 0; r < 4; ++r) {
                        const float m  = fmaf(acc_hl[pbi][csi][r], 4.8828125e-4f,
                                              acc_hh[pbi][csi][r]) * 0.015625f;
                        const float T  = s_frag[pbi * 4 + r] + se;
                        const float dd = fmaf(-2.0f, m, T);
                        const int   s  = pbi * 4 + r;
                        if (dd < best_d[s]) { best_d[s] = dd; best_i[s] = code; }
                    }
            }
        }
    }

    // ---- argmin reduce: butterfly over the 16-lane col group (lexicographic) ----
    #pragma unroll
    for (int off = 1; off < 16; off <<= 1) {
        #pragma unroll
        for (int s = 0; s < 8; ++s) {
            const float d2 = __shfl_xor(best_d[s], off);
            const int   i2 = __shfl_xor(best_i[s], off);
            if (d2 < best_d[s] || (d2 == best_d[s] && i2 < best_i[s])) {
                best_d[s] = d2; best_i[s] = i2;
            }
        }
    }
    if (ln == 0) {
        #pragma unroll
        for (int pbi = 0; pbi < 2; ++pbi)
            #pragma unroll
            for (int r = 0; r < 4; ++r) {
                ldsFD[w][pbi * 16 + qd * 4 + r] = best_d[pbi * 4 + r];
                ldsFI[w][pbi * 16 + qd * 4 + r] = best_i[pbi * 4 + r];
            }
    }
    __syncthreads();
    if (t < PTB) {
        const int hh  = t >> 5;
        const int r32 = t & 31;
        float bd = 3.4e38f; int bi = 0;
        #pragma unroll
        for (int qq = 0; qq < 4; ++qq) {
            const int wv = hh + qq * 2;
            const float d2 = ldsFD[wv][r32];
            const int   i2 = ldsFI[wv][r32];
            if (d2 < bd || (d2 == bd && i2 < bi)) { bd = d2; bi = i2; }
        }
        ldsI[t] = bi;
        out[(size_t)IDX_OFF + n0 + t] = (float)bi;
    }
    __syncthreads();

    // ---- epilogue: gather e row, straight-through out, loss partial ----
    double lsum = 0.0;
    {
        const int p  = t & 63;
        const int cg = t >> 6;
        const int row = ldsI[p];
        const float* erow = emb + (size_t)row * DDIM;
        float* ob = out + (size_t)b * CHW + hw0 + p;
        for (int q = 0; q < 32; ++q) {
            const int c = cg * 32 + q;
            const float e  = erow[c];
            const float xx = xs[(size_t)c * HWSZ + p];
            const float diff = e - xx;             // fl(x_q - xt)
            ob[(size_t)c * HWSZ] = xx + diff;      // straight-through rounding
            lsum += (double)diff * (double)diff;
        }
    }
    #pragma unroll
    for (int off = 32; off > 0; off >>= 1)
        lsum += __shfl_xor(lsum, off);
    if ((t & 63) == 0) ldsL[t >> 6] = lsum;
    __syncthreads();
    if (t == 0) {
        double tot = 0.0;
        #pragma unroll
        for (int wv = 0; wv < 8; ++wv) tot += ldsL[wv];
        atomicAdd(&out[LOSS_OFF], (float)(tot * (1.25 / 4194304.0)));
    }
}

extern "C" void kernel_launch(void* const* d_in, const int* in_sizes, int n_in,
                              void* d_out, int out_size, void* d_ws, size_t ws_size,
                              hipStream_t stream) {
    (void)in_sizes; (void)n_in; (void)out_size; (void)ws_size;
    const float* x   = (const float*)d_in[0];
    const float* emb = (const float*)d_in[1];
    float* out = (float*)d_out;
    unsigned short* ehi = (unsigned short*)d_ws;
    unsigned short* elo = ehi + EHI_WORDS;
    float*          wse = (float*)((char*)d_ws + SE_OFF_B);
    hipMemsetAsync((char*)d_out + (size_t)LOSS_OFF * sizeof(float), 0, sizeof(float), stream);
    prep_kernel<<<256, 256, 0, stream>>>(emb, ehi, elo, wse);
    vq_kernel<<<NPTS / PTB, 512, 0, stream>>>(x, ehi, elo, wse, emb, out);
}